// Round 3
// baseline (154.047 us; speedup 1.0000x reference)
//
#include <hip/hip_runtime.h>
#include <math.h>

// Problem constants
#define NPIX   65536      // 64*32*32 pixels
#define NELEM  655360     // 64*10*32*32 elements of z
#define NCODE  1024
#define CSTRIDE 1024      // stride between channels in z (h*w)
#define BSTRIDE 10240     // stride between batches in z (c*h*w)
#define NBLK   1024       // 1024 blocks x 256 threads, 4 threads/pixel

// Any code flipping a channel with |v| > SOFT_T has exp(t) == 0 in fp32
// (t < -88 underflows), matching the reference's own fp32 softmax.
#define SOFT_T 0.22f

// d_out layout (floats):
//   [0, 655360)          z_q_out (sign(z), b,c,h,w like z)
//   [655360..655364]     loss, commit, ent_loss, per_sample_entropy, avg_entropy
//   [655365, 720901)     min_encoding_indices (as float), [b,h,w]
//
// d_ws floats: [0]=commit_sum, [1]=sum over pixels of (sum_n p log p),
//              [2..2+1024) = hist, [1026] = done-counter (as uint)

__global__ void __launch_bounds__(256)
k_pixel(const float* __restrict__ z,
        float* __restrict__ zq,
        float* __restrict__ out_idx,
        float* __restrict__ out_sc,
        float* __restrict__ ws) {
    __shared__ float hist[NCODE];
    __shared__ float s_av[256 * 11];          // stride 11: conflict-free
    __shared__ unsigned char s_ch[256 * 11];
    __shared__ float red[256];
    __shared__ int s_last;

    int tid = threadIdx.x;
    for (int i = tid; i < NCODE; i += 256) hist[i] = 0.f;
    __syncthreads();

    int gt  = blockIdx.x * 256 + tid;
    int p   = gt >> 2;                        // pixel id: b*1024 + h*32 + w
    int sub = gt & 3;                         // which quarter of the subsets
    int b = p >> 10;
    int hw = p & 1023;
    const float* zp = z  + b * BSTRIDE + hw;
    float*       qp = zq + b * BSTRIDE + hw;

    float* av = &s_av[tid * 11];
    unsigned char* ch = &s_ch[tid * 11];

    int idx = 0, k = 0;
    float commit = 0.f;
    float v[10];
#pragma unroll
    for (int c = 0; c < 10; ++c) {
        float x = zp[c * CSTRIDE];
        v[c] = x;
        float h = (x > 0.f) ? 1.f : -1.f;
        float d = h - x;
        commit = fmaf(d, d, commit);
        if (x > 0.f) idx |= (1 << c);
        float a = fabsf(x);
        if (a < SOFT_T) { av[k] = a; ch[k] = (unsigned char)c; ++k; }
    }
    // split the 10 sign-stores across the 4 sub-lanes
#pragma unroll
    for (int c = 0; c < 10; ++c)
        if ((c & 3) == sub) qp[c * CSTRIDE] = (v[c] > 0.f) ? 1.f : -1.f;
    if (sub == 0) out_idx[p] = (float)idx;

    // this lane handles subsets whose top-2 soft-channel bits == sub
    int kl = (k > 2) ? (k - 2) : 0;           // low-bit count to enumerate
    int nIter = 1 << kl;
    bool active = sub < (1 << (k < 2 ? k : 2));
    float s0 = 0.f; int cm0 = 0;
    if (k >= 1 && (sub & 1)) { s0 += av[k - 1]; cm0 |= 1 << ch[k - 1]; }
    if (k >= 2 && (sub & 2)) { s0 += av[k - 2]; cm0 |= 1 << ch[k - 2]; }

    // pass 1: partial Z = sum exp(t), U = sum exp(t)*t (Gray-code order)
    float Z = 0.f, U = 0.f;
    if (active) {
        float t0 = -400.f * s0;
        float e0 = __expf(t0);
        Z = e0; U = e0 * t0;
        int gray = 0; float s = s0;
        for (int m = 1; m < nIter; ++m) {
            int bit = __ffs(m) - 1;
            int bm = 1 << bit;
            gray ^= bm;
            float a = av[bit];
            s += (gray & bm) ? a : -a;
            float t = -400.f * s;
            float e = __expf(t);
            Z += e;
            U = fmaf(e, t, U);
        }
    }
    // combine across the 4 sub-lanes (adjacent lanes, same wave)
    Z += __shfl_xor(Z, 1); Z += __shfl_xor(Z, 2);
    U += __shfl_xor(U, 1); U += __shfl_xor(U, 2);
    float invZ = 1.f / Z;
    float plogp = U * invZ - logf(Z);         // sum_n p_n log p_n

    // pass 2: histogram of probs
    if (active) {
        atomicAdd(&hist[idx ^ cm0], __expf(-400.f * s0) * invZ);
        int gray = 0, cmask = cm0; float s = s0;
        for (int m = 1; m < nIter; ++m) {
            int bit = __ffs(m) - 1;
            int bm = 1 << bit;
            gray ^= bm;
            cmask ^= 1 << ch[bit];
            float a = av[bit];
            s += (gray & bm) ? a : -a;
            float e = __expf(-400.f * s);
            atomicAdd(&hist[idx ^ cmask], e * invZ);
        }
    }

    // block-reduce plogp then commit (count each pixel once: sub==0 lane)
    red[tid] = (sub == 0) ? plogp : 0.f;
    __syncthreads();
    for (int st = 128; st > 0; st >>= 1) {
        if (tid < st) red[tid] += red[tid + st];
        __syncthreads();
    }
    if (tid == 0) atomicAdd(&ws[1], red[0]);
    __syncthreads();
    red[tid] = (sub == 0) ? commit : 0.f;
    __syncthreads();
    for (int st = 128; st > 0; st >>= 1) {
        if (tid < st) red[tid] += red[tid + st];
        __syncthreads();
    }
    if (tid == 0) atomicAdd(&ws[0], red[0]);

    __syncthreads();
    for (int i = tid; i < NCODE; i += 256)
        if (hist[i] != 0.f) atomicAdd(&ws[2 + i], hist[i]);

    // last block computes the final scalars (replaces k_final launch)
    __threadfence();
    if (tid == 0) {
        unsigned done = atomicAdd((unsigned*)&ws[1026], 1u);
        s_last = (done == NBLK - 1);
    }
    __syncthreads();
    if (s_last) {
        float acc = 0.f;
        for (int i = tid; i < NCODE; i += 256) {
            float a = atomicAdd(&ws[2 + i], 0.f) * (1.f / 65536.f);
            acc -= a * logf(a + 1e-5f);
        }
        red[tid] = acc;
        __syncthreads();
        for (int st = 128; st > 0; st >>= 1) {
            if (tid < st) red[tid] += red[tid + st];
            __syncthreads();
        }
        if (tid == 0) {
            float avg_entropy = red[0];                       // * ENT_GAMMA
            float pse = -atomicAdd(&ws[1], 0.f) * (1.f / 65536.f);
            float cl  = 0.25f * atomicAdd(&ws[0], 0.f) * (1.f / (float)NELEM);
            float ent_loss = 0.1f * (pse - avg_entropy);
            out_sc[0] = cl + ent_loss;                        // loss
            out_sc[1] = cl;
            out_sc[2] = ent_loss;
            out_sc[3] = pse;
            out_sc[4] = avg_entropy;
        }
    }
}

extern "C" void kernel_launch(void* const* d_in, const int* in_sizes, int n_in,
                              void* d_out, int out_size, void* d_ws, size_t ws_size,
                              hipStream_t stream) {
    const float* z = (const float*)d_in[0];
    float* out = (float*)d_out;
    float* ws = (float*)d_ws;

    // zero accumulators + hist + done-counter
    hipMemsetAsync(ws, 0, (2 + NCODE + 1) * sizeof(float), stream);
    k_pixel<<<NBLK, 256, 0, stream>>>(z, out, out + NELEM + 5, out + NELEM, ws);
}

// Round 4
// 75.758 us; speedup vs baseline: 2.0334x; 2.0334x over previous
//
#include <hip/hip_runtime.h>
#include <math.h>

// Problem constants
#define NPIX    65536     // 64*32*32 pixels
#define NELEM   655360    // 64*10*32*32 elements of z
#define NCODE   1024
#define CSTRIDE 1024      // stride between channels in z (h*w)
#define BSTRIDE 10240     // stride between batches in z (c*h*w)
#define NCOPY   16        // spread histogram copies (contention /16)

// Any code flipping a channel with |v| > SOFT_T has exp(t) == 0 in fp32
// (t < -88 underflows), matching the reference's own fp32 softmax.
#define SOFT_T 0.22f

// d_out layout (floats):
//   [0, 655360)        z_q_out (sign(z), b,c,h,w like z)
//   [655360..655364]   loss, commit, ent_loss, per_sample_entropy, avg_entropy
//   [655365, 720901)   min_encoding_indices (as float), [b,h,w]
//
// d_ws floats: [0]=commit_sum, [1]=sum over pixels of (sum_n p log p),
//              [2 .. 2+NCOPY*1024) = partial histograms

__global__ void __launch_bounds__(256)
k_pixel(const float* __restrict__ z,
        float* __restrict__ zq,
        float* __restrict__ out_idx,
        float* __restrict__ ws) {
    __shared__ float hist[NCODE];
    __shared__ uint2 s_e[256 * 11];   // per-thread soft table: (|v| bits, chan bitmask)
    __shared__ float2 red[256];

    int tid = threadIdx.x;
    for (int i = tid; i < NCODE; i += 256) hist[i] = 0.f;
    __syncthreads();

    int p = blockIdx.x * 256 + tid;   // pixel id: b*1024 + h*32 + w
    int b = p >> 10;
    int hw = p & 1023;
    const float* zp = z  + b * BSTRIDE + hw;
    float*       qp = zq + b * BSTRIDE + hw;
    uint2* et = &s_e[tid * 11];

    // --- per-pixel: signs, commit, index, and PRODUCT-FORM softmax stats ---
    // Z = prod_c (1 + e_c),  sum_n p log p = sum_c t_c*e_c/(1+e_c) - log Z,
    // with e_c = exp(-400*|v_c|).  Exact: hard channels give e_c == 0 in fp32.
    int idx = 0, k = 0;
    float commit = 0.f;
    float Z = 1.f, W = 0.f;
#pragma unroll
    for (int c = 0; c < 10; ++c) {
        float x = zp[c * CSTRIDE];
        float h = (x > 0.f) ? 1.f : -1.f;
        qp[c * CSTRIDE] = h;                       // dense, coalesced stores
        float d = h - x;
        commit = fmaf(d, d, commit);
        if (x > 0.f) idx |= (1 << c);
        float a = fabsf(x);
        float t = -400.f * a;
        float e = __expf(t);
        float r = e / (1.f + e);                   // flip probability p_c
        Z *= (1.f + e);
        W = fmaf(t, r, W);
        if (a < SOFT_T) {
            uint2 u; u.x = __float_as_uint(a); u.y = 1u << c;
            et[k] = u; ++k;
        }
    }
    out_idx[p] = (float)idx;
    float invZ = 1.f / Z;
    float plogp = W - logf(Z);                     // sum_n p_n log p_n  (<=0)

    // --- pass 2: histogram over soft-channel subsets (Gray code, prefetched) ---
    int nsub = 1 << k;
    atomicAdd(&hist[idx], invZ);                   // empty subset: p = 1/Z
    float s = 0.f;
    int gray = 0;
    unsigned cmask = 0;
    uint2 cur = et[0];                             // bit(m=1) == 0
    for (int m = 1; m < nsub; ++m) {
        int bit  = __ffs(m) - 1;     (void)bit;
        int nbit = __ffs(m + 1) - 1;
        uint2 nxt = et[nbit];                      // prefetch next entry
        int bm = 1 << (__ffs(m) - 1);
        gray ^= bm;
        float a = __uint_as_float(cur.x);
        s += (gray & bm) ? a : -a;
        cmask ^= cur.y;
        atomicAdd(&hist[idx ^ cmask], __expf(-400.f * s) * invZ);
        cur = nxt;
    }

    // --- block-reduce (plogp, commit) together ---
    red[tid] = make_float2(plogp, commit);
    __syncthreads();
    for (int st = 128; st > 0; st >>= 1) {
        if (tid < st) {
            red[tid].x += red[tid + st].x;
            red[tid].y += red[tid + st].y;
        }
        __syncthreads();
    }
    if (tid == 0) {
        atomicAdd(&ws[1], red[0].x);
        atomicAdd(&ws[0], red[0].y);
    }

    // --- flush block histogram into one of NCOPY spread copies ---
    float* hcopy = ws + 2 + (size_t)(blockIdx.x & (NCOPY - 1)) * NCODE;
    for (int i = tid; i < NCODE; i += 256) {
        float hv = hist[i];
        if (hv != 0.f) atomicAdd(&hcopy[i], hv);
    }
}

__global__ void __launch_bounds__(1024)
k_final(const float* __restrict__ ws, float* __restrict__ out_sc) {
    __shared__ float red[1024];
    int t = threadIdx.x;
    float a = 0.f;
#pragma unroll
    for (int j = 0; j < NCOPY; ++j) a += ws[2 + j * NCODE + t];
    a *= (1.f / 65536.f);                          // avg_probs[t]
    red[t] = -a * logf(a + 1e-5f);
    __syncthreads();
    for (int s = 512; s > 0; s >>= 1) {
        if (t < s) red[t] += red[t + s];
        __syncthreads();
    }
    if (t == 0) {
        float avg_entropy = red[0];                // * ENT_GAMMA (1.0)
        float pse = -ws[1] * (1.f / 65536.f);      // per_sample_entropy
        float cl  = 0.25f * ws[0] * (1.f / (float)NELEM);
        float el  = 0.1f * (pse - avg_entropy);
        out_sc[0] = cl + el;                       // loss
        out_sc[1] = cl;
        out_sc[2] = el;
        out_sc[3] = pse;
        out_sc[4] = avg_entropy;
    }
}

extern "C" void kernel_launch(void* const* d_in, const int* in_sizes, int n_in,
                              void* d_out, int out_size, void* d_ws, size_t ws_size,
                              hipStream_t stream) {
    const float* z = (const float*)d_in[0];
    float* out = (float*)d_out;
    float* ws = (float*)d_ws;

    hipMemsetAsync(ws, 0, (2 + NCOPY * NCODE) * sizeof(float), stream);
    k_pixel<<<NPIX / 256, 256, 0, stream>>>(z, out, out + NELEM + 5, ws);
    k_final<<<1, 1024, 0, stream>>>(ws, out + NELEM);
}